// Round 14
// baseline (85.906 us; speedup 1.0000x reference)
//
#include <hip/hip_runtime.h>
#include <hip/hip_bf16.h>
#include <math.h>

#define B_ 8
#define H_ 128
#define W_ 128
#define C_ 3
#define D_ 132
#define HW_ (H_*W_)            // 16384
#define RPB_ (HW_+1)           // 16385 rows per batch (incl. zero row)
#define NROWS_ (B_*RPB_)       // 131080
#define AROWS_ 131136
#define ASTRIDE_ 136           // conv LDS As row stride (elems)
#define MSTRIDE_ 168           // M row stride
#define MROWS_ 136
#define MELEMS_ (MROWS_*MSTRIDE_)   // 22848 real elems
#define MALLOC_ 23040               // padded to 45 KiB
#define NK_ 65536
#define NOUT_ (B_*NK_)         // 524288

typedef __attribute__((ext_vector_type(8))) short short8v;
typedef __attribute__((ext_vector_type(8))) unsigned short ushort8v;
typedef __attribute__((ext_vector_type(4))) float f32x4;

#define GLOAD16(gp, lp) __builtin_amdgcn_global_load_lds( \
  (const __attribute__((address_space(1))) unsigned int*)(gp), \
  (__attribute__((address_space(3))) unsigned int*)(void*)(lp), 16, 0, 0)

__device__ inline float bf2f(unsigned short u) {
  return __uint_as_float(((unsigned)u) << 16);
}
__device__ inline unsigned short f2bf(float f) {
  __hip_bfloat16 hb = __float2bfloat16(f);
  return *(unsigned short*)&hb;
}

// ---------------------------------------------------------------------------
// K0: M_bf16 [136][168]: a<132 -> Ks^T Qs; a==132 -> u; a==133 -> v; else 0.
// Cols >=132 zero; pad to 23040 zero. c = ks_b . qs_b.
// ---------------------------------------------------------------------------
__global__ __launch_bounds__(512) void prep_kernel(
    const float* __restrict__ ks_w, const float* __restrict__ ks_b,
    const float* __restrict__ qs_w, const float* __restrict__ qs_b,
    unsigned short* __restrict__ Mb, float* __restrict__ cc) {
  int idx = blockIdx.x * 512 + threadIdx.x;
  if (idx >= MALLOC_) return;
  float val = 0.f;
  if (idx < MELEMS_) {
    int a = idx / MSTRIDE_;
    int k = idx - a * MSTRIDE_;
    if (k < D_) {
      if (a < D_) {
        for (int o = 0; o < D_; ++o)
          val = fmaf(ks_w[o * D_ + a], qs_w[o * D_ + k], val);
      } else if (a == 132) {
        for (int o = 0; o < D_; ++o)
          val = fmaf(qs_b[o], ks_w[o * D_ + k], val);
      } else if (a == 133) {
        for (int o = 0; o < D_; ++o)
          val = fmaf(ks_b[o], qs_w[o * D_ + k], val);
      }
    }
  }
  Mb[idx] = f2bf(val);
  if (idx == 0) {
    float s = 0.f;
    for (int o = 0; o < D_; ++o) s = fmaf(ks_b[o], qs_b[o], s);
    cc[0] = s;
  }
}

// ---------------------------------------------------------------------------
// conv helper: one (d, w0) item -> 16 conv outputs + partial ssq
// ---------------------------------------------------------------------------
__device__ __forceinline__ float conv_item16(
    const float* __restrict__ in_s, const float* __restrict__ w_s,
    float bias, int d, int w0, float* acc) {
  float wt[27];
#pragma unroll
  for (int j = 0; j < 27; ++j) wt[j] = w_s[d * 27 + j];
#pragma unroll
  for (int i = 0; i < 16; ++i) acc[i] = bias;
#pragma unroll
  for (int ck = 0; ck < 9; ++ck) {
    const float4* p4 = (const float4*)(in_s + ck * 132);
    float v[20];
#pragma unroll
    for (int j = 0; j < 5; ++j) {
      float4 t4 = p4[(w0 >> 2) + j];   // wave-broadcast reads
      v[4 * j + 0] = t4.x; v[4 * j + 1] = t4.y;
      v[4 * j + 2] = t4.z; v[4 * j + 3] = t4.w;
    }
#pragma unroll
    for (int i = 0; i < 16; ++i) {
      float a0 = fmaf(v[i], wt[ck * 3 + 0], acc[i]);
      float a1 = fmaf(v[i + 1], wt[ck * 3 + 1], a0);
      acc[i] = fmaf(v[i + 2], wt[ck * 3 + 2], a1);
    }
  }
  float ssq = 0.f;
#pragma unroll
  for (int i = 0; i < 16; ++i) ssq = fmaf(acc[i], acc[i], ssq);
  return ssq;
}

// ---------------------------------------------------------------------------
// K1 conv-only (high occupancy: no M in LDS; ~35 KB -> 3 blocks/CU):
//   A: conv+norm -> regs; B: f -> As[128][136] (LDS); D: memcpy As->fmain
//   + ft rows (= As cols 128..135 = [f128..131, 1.0, 0(su), 0, 0]).
// bid==1024: zero rows for all batches.
// ---------------------------------------------------------------------------
__global__ __launch_bounds__(512, 6) void conv_kernel(
    const float* __restrict__ img, const float* __restrict__ cw,
    const float* __restrict__ cb, unsigned short* __restrict__ fmain,
    unsigned short* __restrict__ ft, const float* __restrict__ cc,
    unsigned short* __restrict__ zmain, unsigned short* __restrict__ zt) {
  int bid = blockIdx.x;
  int tid = threadIdx.x;

  if (bid == B_ * H_) {
    float cval = cc[0];
    for (int i = tid; i < B_ * 128; i += 512) {
      int b = i >> 7, c = i & 127;
      size_t r = (size_t)b * RPB_ + HW_;
      fmain[r * 128 + c] = 0;
      zmain[r * 128 + c] = 0;
    }
    if (tid < B_) {
      size_t r = (size_t)tid * RPB_ + HW_;
      ushort8v f8 = {0, 0, 0, 0, 0x3F80, 0, 0, 0};          // [0..,1,su=0,0,0]
      *(ushort8v*)(ft + r * 8) = f8;
      ushort8v z8 = {0, 0, 0, 0, f2bf(cval), 0x3F80, 0, 0}; // [0..,sv+c=c,1,0,0]
      *(ushort8v*)(zt + r * 8) = z8;
    }
    return;
  }

  __shared__ __align__(16) float nscale[132];
  __shared__ __align__(16) char un[34816];   // max(conv scratch 23760, As 34816)
  float* in_s = (float*)un;            // 9*132
  float* w_s  = in_s + 9 * 132;        // 132*27
  float* b_s  = w_s + 132 * 27;        // 132
  float* parts = b_s + 132;            // 8*132
  unsigned short* As = (unsigned short*)un;  // [128][136]

  int b = bid >> 7, h = bid & 127;
  for (int i = tid; i < 9 * 132; i += 512) {
    int ck = i / 132, x = i - ck * 132;
    int c = ck / 3, kh = ck - c * 3;
    int hh = h + kh - 1, ww = x - 1;
    float val = 0.f;
    if (x >= 1 && x <= 128 && hh >= 0 && hh < H_)
      val = img[((size_t)(b * C_ + c) * H_ + hh) * W_ + ww];
    in_s[i] = val;
  }
  for (int i = tid; i < D_ * 27; i += 512) w_s[i] = cw[i];
  if (tid < D_) b_s[tid] = cb[tid];
  __syncthreads();

  // phase A: conv. Items {tid, tid+512, tid+1024 if tid<32}, 16-wide each.
  float acc0[16], acc1[16], acc2[16];
  int i0 = tid, i1 = tid + 512;
  int wg0 = i0 / 132, dd0 = i0 - wg0 * 132;
  int wg1 = i1 / 132, dd1 = i1 - wg1 * 132;
  parts[wg0 * 132 + dd0] = conv_item16(in_s, w_s, b_s[dd0], dd0, wg0 * 16, acc0);
  parts[wg1 * 132 + dd1] = conv_item16(in_s, w_s, b_s[dd1], dd1, wg1 * 16, acc1);
  int dd2 = 0;
  if (tid < 32) {
    dd2 = 100 + tid;
    parts[7 * 132 + dd2] = conv_item16(in_s, w_s, b_s[dd2], dd2, 112, acc2);
  }
  __syncthreads();
  if (tid < 132) {
    float s = 0.f;
#pragma unroll
    for (int rr = 0; rr < 8; ++rr) s += parts[rr * 132 + tid];
    nscale[tid] = 1.f / fmaxf(sqrtf(s), 1e-12f);
  }
  __syncthreads();  // conv scratch dead; As overlay begins

  // phase B: f -> As (LDS only)
  {
    float sc = nscale[dd0];
#pragma unroll
    for (int i = 0; i < 16; ++i)
      As[(wg0 * 16 + i) * ASTRIDE_ + dd0] = f2bf(acc0[i] * sc);
    sc = nscale[dd1];
#pragma unroll
    for (int i = 0; i < 16; ++i)
      As[(wg1 * 16 + i) * ASTRIDE_ + dd1] = f2bf(acc1[i] * sc);
  }
  if (tid < 32) {
    float sc = nscale[dd2];
#pragma unroll
    for (int i = 0; i < 16; ++i)
      As[(112 + i) * ASTRIDE_ + dd2] = f2bf(acc2[i] * sc);
  }
  if (tid < 128) {  // cols 132..135 = [1.0, 0(su), 0, 0]
    uint2 tv; tv.x = 0x3F80u; tv.y = 0u;
    *(uint2*)&As[tid * ASTRIDE_ + 132] = tv;
  }
  __syncthreads();

  // phase D: memcpy As -> fmain (2048 x ushort8) + ft rows (128 x ushort8)
  size_t rowbase = (size_t)b * RPB_ + (size_t)h * W_;
  unsigned short* fmb = fmain + rowbase * 128;
  for (int i2 = tid; i2 < 2176; i2 += 512) {
    if (i2 < 2048) {
      int r = i2 >> 4, m = i2 & 15;
      *(ushort8v*)(fmb + r * 128 + m * 8) = *(const ushort8v*)(As + r * ASTRIDE_ + m * 8);
    } else {
      int r = i2 - 2048;
      *(ushort8v*)(ft + (rowbase + r) * 8) = *(const ushort8v*)(As + r * ASTRIDE_ + 128);
    }
  }
}

// ---------------------------------------------------------------------------
// K2 gemm-only. Stage fmain into As[128][128] with source-side XOR swizzle
// (chunk m' = m ^ (r&7); involution, read side applies same XOR ->
// conflict-free MFMA A-reads). k=128..131 from ftile (ft rows; tail elems
// annihilated by M cols>=132 == 0). After the single staging barrier,
// everything is wave-local: each wave MFMAs, rewrites, and stores ONLY its
// own 16 rows.
// ---------------------------------------------------------------------------
__global__ __launch_bounds__(512, 4) void gemm_kernel(
    const unsigned short* __restrict__ fmain, unsigned short* __restrict__ ft,
    const unsigned short* __restrict__ Mb, const float* __restrict__ cc,
    unsigned short* __restrict__ zmain, unsigned short* __restrict__ zt) {
  int bid = blockIdx.x;
  int tid = threadIdx.x, wave = tid >> 6, lane = tid & 63;
  __shared__ __align__(16) unsigned short Ms[MALLOC_];   // 46080 B
  __shared__ __align__(16) unsigned short As[128 * 128]; // 32768 B (swizzled)
  __shared__ __align__(16) unsigned short ftile[128 * 8];// 2048 B

  int b = bid >> 7, h = bid & 127;
  size_t rowbase = (size_t)b * RPB_ + (size_t)h * W_;

  // stage M (45 x 1KiB)
  for (int ch = wave; ch < 45; ch += 8)
    GLOAD16(Mb + (size_t)ch * 512 + lane * 8, Ms + ch * 512);
  // stage As (32 x 1KiB), source swizzled: LDS(r,m) <- fmain[r][m ^ (r&7)]
  {
    int rloc = lane >> 4, m = lane & 15;
    for (int ch = wave; ch < 32; ch += 8) {
      int r = ch * 4 + rloc;
      int msrc = m ^ (r & 7);
      GLOAD16(fmain + (rowbase + r) * 128 + msrc * 8, As + ch * 512);
    }
  }
  // stage ftile (2 x 1KiB): row = ch2*64 + lane
  for (int ch2 = wave; ch2 < 2; ch2 += 8)
    GLOAD16(ft + (rowbase + ch2 * 64 + lane) * 8, ftile + ch2 * 512);
  __syncthreads();

  // MFMA: wave w owns rows w*16..+15. A row = wave*16 + c15.
  int c15 = lane & 15, kg = lane >> 4;
  int ra = wave * 16 + c15;
  const unsigned short* brow = Ms + c15 * MSTRIDE_ + kg * 8;
  f32x4 acc[9] = {};
#pragma unroll
  for (int ks = 0; ks < 4; ++ks) {
    int cj = ks * 4 + kg;
    short8v af = *(const short8v*)(As + ra * 128 + ((cj ^ (ra & 7)) * 8));
#pragma unroll
    for (int ct = 0; ct < 9; ++ct) {
      short8v bf = *(const short8v*)(brow + ct * 16 * MSTRIDE_ + ks * 32);
      acc[ct] = __builtin_amdgcn_mfma_f32_16x16x32_bf16(af, bf, acc[ct], 0, 0, 0);
    }
  }
  {  // slice 4: k=128..135 from ftile (kg>=1 lanes read same addr: x M-zeros)
    short8v af = *(const short8v*)(ftile + ra * 8);
#pragma unroll
    for (int ct = 0; ct < 9; ++ct) {
      short8v bf = *(const short8v*)(brow + ct * 16 * MSTRIDE_ + 4 * 32);
      acc[ct] = __builtin_amdgcn_mfma_f32_16x16x32_bf16(af, bf, acc[ct], 0, 0, 0);
    }
  }

  // wave-local epilogue: overwrite own rows of As/ftile with z_ext
  float cval = cc[0];
  int r0l = wave * 16 + kg * 4;
#pragma unroll
  for (int ct = 0; ct < 9; ++ct) {
    int col = ct * 16 + c15;
#pragma unroll
    for (int j = 0; j < 4; ++j) {
      int r = r0l + j;
      if (col < 128)
        As[r * 128 + (((col >> 3) ^ (r & 7)) << 3) + (col & 7)] = f2bf(acc[ct][j]);
      else if (col < 132)      ftile[r * 8 + (col - 128)] = f2bf(acc[ct][j]);      // z128..131
      else if (col == 132)     ft[(rowbase + r) * 8 + 5] = f2bf(acc[ct][j]);       // su -> global
      else if (col == 133)     ftile[r * 8 + 4] = f2bf(acc[ct][j] + cval);         // sv+c
      else if (col == 134)     ftile[r * 8 + 5] = 0x3F80;                          // 1.0
      else if (col == 135)     ftile[r * 8 + 6] = 0;
      else if (col == 136)     ftile[r * 8 + 7] = 0;
    }
  }

  // wave-local stores: own 16 rows -> zmain (swizzle-aware) + zt
  unsigned short* zmb = zmain + rowbase * 128;
  for (int i2 = lane; i2 < 256; i2 += 64) {
    int r = wave * 16 + (i2 >> 4), m = i2 & 15;
    *(ushort8v*)(zmb + r * 128 + m * 8) =
        *(const ushort8v*)(As + r * 128 + ((m ^ (r & 7)) * 8));
  }
  if (lane < 16) {
    int r = wave * 16 + lane;
    *(ushort8v*)(zt + (rowbase + r) * 8) = *(const ushort8v*)(ftile + r * 8);
  }
}

// ---------------------------------------------------------------------------
// K3: gather + dot, split-row layout (unchanged from round 13).
// ---------------------------------------------------------------------------
__global__ __launch_bounds__(256) void gather_kernel(
    const int* __restrict__ xi, const int* __restrict__ yi,
    const unsigned short* __restrict__ fmain, const unsigned short* __restrict__ ft,
    const unsigned short* __restrict__ zmain, const unsigned short* __restrict__ zt,
    float* __restrict__ out) {
  const float scale = 0.08703882797784892f;  // 132^-0.5
  int bi = blockIdx.x;
  int b = bi & 7;
  int chunk = bi >> 3;
  int lane = threadIdx.x & 7;
  int rem1 = chunk * 32 + (threadIdx.x >> 3);
  int rem2 = rem1 + 32768;

  size_t ib1 = (size_t)b * NK_ + rem1;
  size_t ib2 = (size_t)b * NK_ + rem2;
  int x1 = xi[ib1], y1 = yi[ib1];
  int x2 = xi[ib2], y2 = yi[ib2];
  size_t bbase = (size_t)b * RPB_;
  const unsigned short* fx1 = fmain + (bbase + x1) * 128;
  const unsigned short* zy1 = zmain + (bbase + y1) * 128;
  const unsigned short* fx2 = fmain + (bbase + x2) * 128;
  const unsigned short* zy2 = zmain + (bbase + y2) * 128;

  int e0 = lane * 16;
  ushort8v a10 = *(const ushort8v*)(fx1 + e0);
  ushort8v a11 = *(const ushort8v*)(fx1 + e0 + 8);
  ushort8v z10 = *(const ushort8v*)(zy1 + e0);
  ushort8v z11 = *(const ushort8v*)(zy1 + e0 + 8);
  ushort8v a20 = *(const ushort8v*)(fx2 + e0);
  ushort8v a21 = *(const ushort8v*)(fx2 + e0 + 8);
  ushort8v z20 = *(const ushort8v*)(zy2 + e0);
  ushort8v z21 = *(const ushort8v*)(zy2 + e0 + 8);
  ushort8v a1t, z1t, a2t, z2t;
  if (lane == 0) {
    a1t = *(const ushort8v*)(ft + (bbase + x1) * 8);
    z1t = *(const ushort8v*)(zt + (bbase + y1) * 8);
    a2t = *(const ushort8v*)(ft + (bbase + x2) * 8);
    z2t = *(const ushort8v*)(zt + (bbase + y2) * 8);
  }

  float acc1 = 0.f, acc2 = 0.f;
#pragma unroll
  for (int t = 0; t < 8; ++t) {
    acc1 = fmaf(bf2f(a10[t]), bf2f(z10[t]), acc1);
    acc2 = fmaf(bf2f(a20[t]), bf2f(z20[t]), acc2);
  }
#pragma unroll
  for (int t = 0; t < 8; ++t) {
    acc1 = fmaf(bf2f(a11[t]), bf2f(z11[t]), acc1);
    acc2 = fmaf(bf2f(a21[t]), bf2f(z21[t]), acc2);
  }
  if (lane == 0) {
#pragma unroll
    for (int t = 0; t < 8; ++t) {
      acc1 = fmaf(bf2f(a1t[t]), bf2f(z1t[t]), acc1);
      acc2 = fmaf(bf2f(a2t[t]), bf2f(z2t[t]), acc2);
    }
  }
  acc1 += __shfl_xor(acc1, 1);
  acc2 += __shfl_xor(acc2, 1);
  acc1 += __shfl_xor(acc1, 2);
  acc2 += __shfl_xor(acc2, 2);
  acc1 += __shfl_xor(acc1, 4);
  acc2 += __shfl_xor(acc2, 4);
  if (lane == 0) {
    out[((size_t)b << 16) | rem1] = acc1 * scale;
    out[((size_t)b << 16) | rem2] = acc2 * scale;
  }
}

// ---------------------------------------------------------------------------
extern "C" void kernel_launch(void* const* d_in, const int* in_sizes, int n_in,
                              void* d_out, int out_size, void* d_ws, size_t ws_size,
                              hipStream_t stream) {
  const int* indices  = (const int*)d_in[0];
  const float* img    = (const float*)d_in[1];
  const float* conv_w = (const float*)d_in[2];
  const float* conv_b = (const float*)d_in[3];
  const float* ks_w   = (const float*)d_in[4];
  const float* ks_b   = (const float*)d_in[5];
  const float* qs_w   = (const float*)d_in[6];
  const float* qs_b   = (const float*)d_in[7];
  float* out = (float*)d_out;

  char* w = (char*)d_ws;
  unsigned short* fmain = (unsigned short*)w;                   // AROWS_*128
  size_t off = (size_t)AROWS_ * 128 * 2;
  unsigned short* zmain = (unsigned short*)(w + off); off += (size_t)AROWS_ * 128 * 2;
  unsigned short* ftl = (unsigned short*)(w + off);   off += (size_t)AROWS_ * 8 * 2;
  unsigned short* ztl = (unsigned short*)(w + off);   off += (size_t)AROWS_ * 8 * 2;
  unsigned short* Mb = (unsigned short*)(w + off);    off += MALLOC_ * 2;
  float* cc = (float*)(w + off);

  const int* xi = indices + (size_t)B_ * NK_;      // indices[1]
  const int* yi = indices + (size_t)2 * B_ * NK_;  // indices[2]

  hipLaunchKernelGGL(prep_kernel, dim3(MALLOC_ / 512), dim3(512), 0, stream,
                     ks_w, ks_b, qs_w, qs_b, Mb, cc);
  hipLaunchKernelGGL(conv_kernel, dim3(B_ * H_ + 1), dim3(512), 0, stream,
                     img, conv_w, conv_b, fmain, ftl, cc, zmain, ztl);
  hipLaunchKernelGGL(gemm_kernel, dim3(B_ * H_), dim3(512), 0, stream,
                     fmain, ftl, Mb, cc, zmain, ztl);
  hipLaunchKernelGGL(gather_kernel, dim3(NOUT_ / 64), dim3(256), 0, stream,
                     xi, yi, fmain, ftl, zmain, ztl, out);
}

// Round 15
// 81.194 us; speedup vs baseline: 1.0580x; 1.0580x over previous
//
#include <hip/hip_runtime.h>
#include <hip/hip_bf16.h>
#include <math.h>

#define B_ 8
#define H_ 128
#define W_ 128
#define C_ 3
#define D_ 132
#define HW_ (H_*W_)            // 16384
#define RPB_ (HW_+1)           // 16385 rows per batch (incl. zero row)
#define NROWS_ (B_*RPB_)       // 131080
#define AROWS_ 131136
#define FSTRIDE_ 136           // LDS As row stride (elems)
#define MSTRIDE_ 168           // M row stride
#define MROWS_ 136
#define MELEMS_ (MROWS_*MSTRIDE_)   // 22848 real elems
#define MALLOC_ 23040               // padded to 45 KiB
#define NK_ 65536
#define NOUT_ (B_*NK_)         // 524288

typedef __attribute__((ext_vector_type(8))) short short8v;
typedef __attribute__((ext_vector_type(8))) unsigned short ushort8v;
typedef __attribute__((ext_vector_type(4))) float f32x4;

#define GLOAD16(gp, lp) __builtin_amdgcn_global_load_lds( \
  (const __attribute__((address_space(1))) unsigned int*)(gp), \
  (__attribute__((address_space(3))) unsigned int*)(void*)(lp), 16, 0, 0)

__device__ inline float bf2f(unsigned short u) {
  return __uint_as_float(((unsigned)u) << 16);
}
__device__ inline unsigned short f2bf(float f) {
  __hip_bfloat16 hb = __float2bfloat16(f);
  return *(unsigned short*)&hb;
}

// ---------------------------------------------------------------------------
// K0: M_bf16 [136][168]: a<132 -> Ks^T Qs; a==132 -> u; a==133 -> v; else 0.
// Cols >=132 zero; pad to 23040 zero. c = ks_b . qs_b.
// ---------------------------------------------------------------------------
__global__ __launch_bounds__(512) void prep_kernel(
    const float* __restrict__ ks_w, const float* __restrict__ ks_b,
    const float* __restrict__ qs_w, const float* __restrict__ qs_b,
    unsigned short* __restrict__ Mb, float* __restrict__ cc) {
  int idx = blockIdx.x * 512 + threadIdx.x;
  if (idx >= MALLOC_) return;
  float val = 0.f;
  if (idx < MELEMS_) {
    int a = idx / MSTRIDE_;
    int k = idx - a * MSTRIDE_;
    if (k < D_) {
      if (a < D_) {
        for (int o = 0; o < D_; ++o)
          val = fmaf(ks_w[o * D_ + a], qs_w[o * D_ + k], val);
      } else if (a == 132) {
        for (int o = 0; o < D_; ++o)
          val = fmaf(qs_b[o], ks_w[o * D_ + k], val);
      } else if (a == 133) {
        for (int o = 0; o < D_; ++o)
          val = fmaf(ks_b[o], qs_w[o * D_ + k], val);
      }
    }
  }
  Mb[idx] = f2bf(val);
  if (idx == 0) {
    float s = 0.f;
    for (int o = 0; o < D_; ++o) s = fmaf(ks_b[o], qs_b[o], s);
    cc[0] = s;
  }
}

// ---------------------------------------------------------------------------
// conv helper: one (d, w0) item -> 16 conv outputs + partial ssq
// ---------------------------------------------------------------------------
__device__ __forceinline__ float conv_item16(
    const float* __restrict__ in_s, const float* __restrict__ w_s,
    float bias, int d, int w0, float* acc) {
  float wt[27];
#pragma unroll
  for (int j = 0; j < 27; ++j) wt[j] = w_s[d * 27 + j];
#pragma unroll
  for (int i = 0; i < 16; ++i) acc[i] = bias;
#pragma unroll
  for (int ck = 0; ck < 9; ++ck) {
    const float4* p4 = (const float4*)(in_s + ck * 132);
    float v[20];
#pragma unroll
    for (int j = 0; j < 5; ++j) {
      float4 t4 = p4[(w0 >> 2) + j];   // wave-broadcast reads
      v[4 * j + 0] = t4.x; v[4 * j + 1] = t4.y;
      v[4 * j + 2] = t4.z; v[4 * j + 3] = t4.w;
    }
#pragma unroll
    for (int i = 0; i < 16; ++i) {
      float a0 = fmaf(v[i], wt[ck * 3 + 0], acc[i]);
      float a1 = fmaf(v[i + 1], wt[ck * 3 + 1], a0);
      acc[i] = fmaf(v[i + 2], wt[ck * 3 + 2], a1);
    }
  }
  float ssq = 0.f;
#pragma unroll
  for (int i = 0; i < 16; ++i) ssq = fmaf(acc[i], acc[i], ssq);
  return ssq;
}

// ---------------------------------------------------------------------------
// K1 fused conv+gemm (round-13 structure, unchanged — best known).
// Output layout SPLIT:
//   fmain[row][128] (256 B, 2 cache lines)  ft[row][8] = [f128..131,1,su,0,0]
//   zmain[row][128]                          zt[row][8] = [z128..131,sv+c,1,0,0]
// LDS: Ms 46080 + nscale/su_s 528 + un 34880 = 81488 <= 81920 -> 2 blocks/CU.
// ---------------------------------------------------------------------------
__global__ __launch_bounds__(512, 4) void fused_conv_gemm_kernel(
    const float* __restrict__ img, const float* __restrict__ cw,
    const float* __restrict__ cb, unsigned short* __restrict__ fmain,
    unsigned short* __restrict__ ft, const unsigned short* __restrict__ Mb,
    const float* __restrict__ cc, unsigned short* __restrict__ zmain,
    unsigned short* __restrict__ zt) {
  int bid = blockIdx.x;
  int tid = threadIdx.x;

  if (bid == B_ * H_) {
    float cval = cc[0];
    for (int i = tid; i < B_ * 128; i += 512) {
      int b = i >> 7, c = i & 127;
      size_t r = (size_t)b * RPB_ + HW_;
      fmain[r * 128 + c] = 0;
      zmain[r * 128 + c] = 0;
    }
    if (tid < B_) {
      size_t r = (size_t)tid * RPB_ + HW_;
      ushort8v f8 = {0, 0, 0, 0, 0x3F80, 0, 0, 0};          // [0,0,0,0,1,su=0,0,0]
      *(ushort8v*)(ft + r * 8) = f8;
      ushort8v z8 = {0, 0, 0, 0, f2bf(cval), 0x3F80, 0, 0}; // [0..,sv+c=c,1,0,0]
      *(ushort8v*)(zt + r * 8) = z8;
    }
    return;
  }

  int wave = tid >> 6, lane = tid & 63;
  __shared__ __align__(16) unsigned short Ms[MALLOC_];   // 46080 B
  __shared__ __align__(16) float nscale[132];            // 528 B; su_s overlay
  __shared__ __align__(16) char un[34880];               // union region
  float* in_s = (float*)un;            // 9*132
  float* w_s  = in_s + 9 * 132;        // 132*27
  float* b_s  = w_s + 132 * 27;        // 132
  float* parts = b_s + 132;            // 8*132
  unsigned short* As = (unsigned short*)un;  // [128][136] + 32 pad shorts
  unsigned short* su_s = (unsigned short*)nscale;  // after phase B

  for (int ch = wave; ch < 45; ch += 8)
    GLOAD16(Mb + (size_t)ch * 512 + lane * 8, Ms + ch * 512);

  int b = bid >> 7, h = bid & 127;
  for (int i = tid; i < 9 * 132; i += 512) {
    int ck = i / 132, x = i - ck * 132;
    int c = ck / 3, kh = ck - c * 3;
    int hh = h + kh - 1, ww = x - 1;
    float val = 0.f;
    if (x >= 1 && x <= 128 && hh >= 0 && hh < H_)
      val = img[((size_t)(b * C_ + c) * H_ + hh) * W_ + ww];
    in_s[i] = val;
  }
  for (int i = tid; i < D_ * 27; i += 512) w_s[i] = cw[i];
  if (tid < D_) b_s[tid] = cb[tid];
  __syncthreads();

  // phase A: conv. Items {tid, tid+512, tid+1024 if tid<32}, 16-wide each.
  float acc0[16], acc1[16], acc2[16];
  int i0 = tid, i1 = tid + 512;
  int wg0 = i0 / 132, dd0 = i0 - wg0 * 132;
  int wg1 = i1 / 132, dd1 = i1 - wg1 * 132;
  parts[wg0 * 132 + dd0] = conv_item16(in_s, w_s, b_s[dd0], dd0, wg0 * 16, acc0);
  parts[wg1 * 132 + dd1] = conv_item16(in_s, w_s, b_s[dd1], dd1, wg1 * 16, acc1);
  int dd2 = 0;
  if (tid < 32) {
    dd2 = 100 + tid;
    parts[7 * 132 + dd2] = conv_item16(in_s, w_s, b_s[dd2], dd2, 112, acc2);
  }
  __syncthreads();
  if (tid < 132) {
    float s = 0.f;
#pragma unroll
    for (int rr = 0; rr < 8; ++rr) s += parts[rr * 132 + tid];
    nscale[tid] = 1.f / fmaxf(sqrtf(s), 1e-12f);
  }
  __syncthreads();  // conv scratch dead; As overlay begins

  // phase B: write f (bf16) into As (LDS only)
  {
    float sc = nscale[dd0];
#pragma unroll
    for (int i = 0; i < 16; ++i)
      As[(wg0 * 16 + i) * FSTRIDE_ + dd0] = f2bf(acc0[i] * sc);
    sc = nscale[dd1];
#pragma unroll
    for (int i = 0; i < 16; ++i)
      As[(wg1 * 16 + i) * FSTRIDE_ + dd1] = f2bf(acc1[i] * sc);
  }
  if (tid < 32) {
    float sc = nscale[dd2];
#pragma unroll
    for (int i = 0; i < 16; ++i)
      As[(112 + i) * FSTRIDE_ + dd2] = f2bf(acc2[i] * sc);
  }
  if (tid < 128) {  // As row tails: cols 132..135 = [1.0, 0, 0, 0]
    uint2 tv; tv.x = 0x3F80u; tv.y = 0u;
    *(uint2*)&As[tid * FSTRIDE_ + 132] = tv;
  }
  if (tid < 32) As[128 * FSTRIDE_ + tid] = 0;  // wrap pad for K-slice 5
  __syncthreads();  // As = flat tile; nscale dead -> su_s overlay OK

  // phase C1: memcpy As main -> fmain; save f-tails; MFMA (reads only)
  size_t rowbase = (size_t)b * RPB_ + (size_t)h * W_;
  unsigned short* fmb = fmain + rowbase * 128;
  for (int i2 = tid; i2 < 2048; i2 += 512) {
    int r = i2 >> 4, c8 = i2 & 15;
    *(ushort8v*)(fmb + r * 128 + c8 * 8) = *(const ushort8v*)(As + r * FSTRIDE_ + c8 * 8);
  }
  uint2 ftl = {0, 0};
  if (tid < 128) ftl = *(const uint2*)&As[tid * FSTRIDE_ + 128];  // f128..131

  int c15 = lane & 15, kg = lane >> 4;
  const unsigned short* arow = As + (wave * 16 + c15) * FSTRIDE_ + kg * 8;
  const unsigned short* brow = Ms + c15 * MSTRIDE_ + kg * 8;
  f32x4 acc[9] = {};
#pragma unroll
  for (int ks = 0; ks < 5; ++ks) {
    short8v af = *(const short8v*)(arow + ks * 32);
#pragma unroll
    for (int ct = 0; ct < 9; ++ct) {
      short8v bf = *(const short8v*)(brow + ct * 16 * MSTRIDE_ + ks * 32);
      acc[ct] = __builtin_amdgcn_mfma_f32_16x16x32_bf16(af, bf, acc[ct], 0, 0, 0);
    }
  }
  __syncthreads();  // all As reads retired; fmain stores drained

  // phase C2: overwrite OWN wave's 16 As rows with z_ext; su -> su_s (LDS)
  float cval = cc[0];
  int r0 = wave * 16 + kg * 4;
#pragma unroll
  for (int ct = 0; ct < 9; ++ct) {
    int col = ct * 16 + c15;
#pragma unroll
    for (int j = 0; j < 4; ++j) {
      int r = r0 + j;
      if (col < D_)            As[r * FSTRIDE_ + col] = f2bf(acc[ct][j]);
      else if (col == 132)     su_s[r] = f2bf(acc[ct][j]);                       // su
      else if (col == 133)     As[r * FSTRIDE_ + 132] = f2bf(acc[ct][j] + cval); // sv+c
      else if (col == 134)     As[r * FSTRIDE_ + 133] = 0x3F80;                  // 1.0
      else if (col == 135)     As[r * FSTRIDE_ + 134] = 0;
      else if (col == 136)     As[r * FSTRIDE_ + 135] = 0;
    }
  }
  __syncthreads();  // z_ext tile complete in As; su_s complete

  // phase D: memcpy As main -> zmain; assemble zt / ft
  unsigned short* zmb = zmain + rowbase * 128;
  for (int i2 = tid; i2 < 2048; i2 += 512) {
    int r = i2 >> 4, c8 = i2 & 15;
    *(ushort8v*)(zmb + r * 128 + c8 * 8) = *(const ushort8v*)(As + r * FSTRIDE_ + c8 * 8);
  }
  if (tid < 128) {
    *(ushort8v*)(zt + (rowbase + tid) * 8) = *(const ushort8v*)(As + tid * FSTRIDE_ + 128);
    ushort8v f8;
    f8[0] = (unsigned short)(ftl.x & 0xFFFFu);
    f8[1] = (unsigned short)(ftl.x >> 16);
    f8[2] = (unsigned short)(ftl.y & 0xFFFFu);
    f8[3] = (unsigned short)(ftl.y >> 16);
    f8[4] = 0x3F80;
    f8[5] = su_s[tid];
    f8[6] = 0;
    f8[7] = 0;
    *(ushort8v*)(ft + (rowbase + tid) * 8) = f8;
  }
}

// ---------------------------------------------------------------------------
// K3: gather + dot, split-row layout. XCD batch-affinity (b = blockIdx & 7),
// 2 outputs/thread within the same batch. NEW: balanced tails — lane t
// handles tail element t (2-B loads, one 16-B segment per side, L2-resident)
// instead of lane 0 serially processing all 8 (removes lane-0 critical path).
// ---------------------------------------------------------------------------
__global__ __launch_bounds__(256) void gather_kernel(
    const int* __restrict__ xi, const int* __restrict__ yi,
    const unsigned short* __restrict__ fmain, const unsigned short* __restrict__ ft,
    const unsigned short* __restrict__ zmain, const unsigned short* __restrict__ zt,
    float* __restrict__ out) {
  const float scale = 0.08703882797784892f;  // 132^-0.5
  int bi = blockIdx.x;                 // [0, 8192)
  int b = bi & 7;
  int chunk = bi >> 3;                 // [0, 1024)
  int lane = threadIdx.x & 7;
  int rem1 = chunk * 32 + (threadIdx.x >> 3);
  int rem2 = rem1 + 32768;             // same batch

  size_t ib1 = (size_t)b * NK_ + rem1;
  size_t ib2 = (size_t)b * NK_ + rem2;
  int x1 = xi[ib1], y1 = yi[ib1];
  int x2 = xi[ib2], y2 = yi[ib2];
  size_t bbase = (size_t)b * RPB_;
  const unsigned short* fx1 = fmain + (bbase + x1) * 128;
  const unsigned short* zy1 = zmain + (bbase + y1) * 128;
  const unsigned short* fx2 = fmain + (bbase + x2) * 128;
  const unsigned short* zy2 = zmain + (bbase + y2) * 128;

  int e0 = lane * 16;
  // issue ALL loads up front (main 16B x8 + tail 2B x4 per thread)
  ushort8v a10 = *(const ushort8v*)(fx1 + e0);
  ushort8v a11 = *(const ushort8v*)(fx1 + e0 + 8);
  ushort8v z10 = *(const ushort8v*)(zy1 + e0);
  ushort8v z11 = *(const ushort8v*)(zy1 + e0 + 8);
  ushort8v a20 = *(const ushort8v*)(fx2 + e0);
  ushort8v a21 = *(const ushort8v*)(fx2 + e0 + 8);
  ushort8v z20 = *(const ushort8v*)(zy2 + e0);
  ushort8v z21 = *(const ushort8v*)(zy2 + e0 + 8);
  unsigned short a1t = ft[(bbase + x1) * 8 + lane];
  unsigned short z1t = zt[(bbase + y1) * 8 + lane];
  unsigned short a2t = ft[(bbase + x2) * 8 + lane];
  unsigned short z2t = zt[(bbase + y2) * 8 + lane];

  float acc1 = bf2f(a1t) * bf2f(z1t);   // distributed tail contribution
  float acc2 = bf2f(a2t) * bf2f(z2t);
#pragma unroll
  for (int t = 0; t < 8; ++t) {
    acc1 = fmaf(bf2f(a10[t]), bf2f(z10[t]), acc1);
    acc2 = fmaf(bf2f(a20[t]), bf2f(z20[t]), acc2);
  }
#pragma unroll
  for (int t = 0; t < 8; ++t) {
    acc1 = fmaf(bf2f(a11[t]), bf2f(z11[t]), acc1);
    acc2 = fmaf(bf2f(a21[t]), bf2f(z21[t]), acc2);
  }
  acc1 += __shfl_xor(acc1, 1);
  acc2 += __shfl_xor(acc2, 1);
  acc1 += __shfl_xor(acc1, 2);
  acc2 += __shfl_xor(acc2, 2);
  acc1 += __shfl_xor(acc1, 4);
  acc2 += __shfl_xor(acc2, 4);
  if (lane == 0) {
    out[((size_t)b << 16) | rem1] = acc1 * scale;
    out[((size_t)b << 16) | rem2] = acc2 * scale;
  }
}

// ---------------------------------------------------------------------------
extern "C" void kernel_launch(void* const* d_in, const int* in_sizes, int n_in,
                              void* d_out, int out_size, void* d_ws, size_t ws_size,
                              hipStream_t stream) {
  const int* indices  = (const int*)d_in[0];
  const float* img    = (const float*)d_in[1];
  const float* conv_w = (const float*)d_in[2];
  const float* conv_b = (const float*)d_in[3];
  const float* ks_w   = (const float*)d_in[4];
  const float* ks_b   = (const float*)d_in[5];
  const float* qs_w   = (const float*)d_in[6];
  const float* qs_b   = (const float*)d_in[7];
  float* out = (float*)d_out;

  char* w = (char*)d_ws;
  unsigned short* fmain = (unsigned short*)w;                   // AROWS_*128
  size_t off = (size_t)AROWS_ * 128 * 2;
  unsigned short* zmain = (unsigned short*)(w + off); off += (size_t)AROWS_ * 128 * 2;
  unsigned short* ftl = (unsigned short*)(w + off);   off += (size_t)AROWS_ * 8 * 2;
  unsigned short* ztl = (unsigned short*)(w + off);   off += (size_t)AROWS_ * 8 * 2;
  unsigned short* Mb = (unsigned short*)(w + off);    off += MALLOC_ * 2;
  float* cc = (float*)(w + off);

  const int* xi = indices + (size_t)B_ * NK_;      // indices[1]
  const int* yi = indices + (size_t)2 * B_ * NK_;  // indices[2]

  hipLaunchKernelGGL(prep_kernel, dim3(MALLOC_ / 512), dim3(512), 0, stream,
                     ks_w, ks_b, qs_w, qs_b, Mb, cc);
  hipLaunchKernelGGL(fused_conv_gemm_kernel, dim3(B_ * H_ + 1), dim3(512), 0, stream,
                     img, conv_w, conv_b, fmain, ftl, Mb, cc, zmain, ztl);
  hipLaunchKernelGGL(gather_kernel, dim3(NOUT_ / 64), dim3(256), 0, stream,
                     xi, yi, fmain, ftl, zmain, ztl, out);
}